// Round 1
// baseline (3793.942 us; speedup 1.0000x reference)
//
#include <hip/hip_runtime.h>
#include <hip/hip_cooperative_groups.h>
#include <stdint.h>

namespace cg = cooperative_groups;

// Problem constants (fixed by setup_inputs)
#define Bn 256
#define Hn 768
#define Tn 128
#define KS 24      // Hn/32 ksteps
#define CBn 48     // col-blocks (j-tiles of 16 hidden units x 3 gates)
#define RGn 4      // row-groups of 64 batch rows
#define NTHR 256   // 4 waves; wave w owns m-tile w (16 rows), all gates, full K
#define NBLK 192   // CBn * RGn
#define SMEM_BYTES 147456  // W slice hi+lo in LDS (dynamic)

typedef __attribute__((ext_vector_type(8))) short short8;   // 8 bf16
typedef __attribute__((ext_vector_type(4))) float floatx4;  // mfma C/D

static __device__ __forceinline__ unsigned short f2bf(float f) {
  unsigned int x = __float_as_uint(f);
  x += 0x7fffu + ((x >> 16) & 1u);
  return (unsigned short)(x >> 16);
}
static __device__ __forceinline__ float bf2f(unsigned short u) {
  return __uint_as_float(((unsigned int)u) << 16);
}

// ---------------------------------------------------------------------------
// Swizzle W_hh (2304x768 fp32 row-major) into slice-contiguous B-fragment
// order, bf16 hi/lo interleaved per chunk (unchanged from previous version).
// ---------------------------------------------------------------------------
__global__ void swz_w(const float* __restrict__ W,
                      unsigned short* __restrict__ wsw) {
  int i = blockIdx.x * blockDim.x + threadIdx.x;
  if (i >= 2304 * (Hn / 8)) return;
  int n  = i / (Hn / 8);
  int k0 = (i % (Hn / 8)) * 8;
  int g = n / Hn, jj = n % Hn;
  int cb = jj >> 4, l15 = jj & 15;
  int ks = k0 >> 5, k8 = (k0 >> 3) & 3;
  int lane = l15 + 16 * k8;
  unsigned short* slice = wsw + (size_t)cb * 73728;
  size_t offh = ((size_t)((g * KS + ks) * 2 + 0)) * 512 + (size_t)lane * 8;
  size_t offl = ((size_t)((g * KS + ks) * 2 + 1)) * 512 + (size_t)lane * 8;
  const float* src = W + (size_t)n * Hn + k0;
  short8 h8, l8;
#pragma unroll
  for (int q = 0; q < 8; ++q) {
    float w = src[q];
    unsigned short hb = f2bf(w);
    h8[q] = (short)hb;
    l8[q] = (short)f2bf(w - bf2f(hb));
  }
  *(short8*)(slice + offh) = h8;
  *(short8*)(slice + offl) = l8;
}

// ---------------------------------------------------------------------------
// Init: h0 planes (bf16 hi/lo) from context; zero ddot.
// hbase layout: [hhi0 | hlo0 | hhi1 | hlo1], each Bn*Hn elements.
// ---------------------------------------------------------------------------
__global__ void init_h(const float* __restrict__ ctx,
                       unsigned short* __restrict__ hbase,
                       float* __restrict__ ddot) {
  int i = blockIdx.x * blockDim.x + threadIdx.x;
  if (i < Bn * Hn) {
    float c = ctx[i];
    unsigned short hb = f2bf(c);
    hbase[i] = hb;                            // hhi0
    hbase[Bn * Hn + i] = f2bf(c - bf2f(hb));  // hlo0
  }
  if (i < Tn * Bn) ddot[i] = 0.f;
}

// ---------------------------------------------------------------------------
// PERSISTENT cooperative kernel: all Tn steps in ONE dispatch.
//  - W slice staged into LDS ONCE (was: re-staged 128x = 27.6 MB/step).
//  - grid.sync() per step replaces the dispatch boundary (release/acquire
//    fences in __ockl_grid_sync give cross-XCD visibility of the h stores).
//  - Double-buffered h planes => one sync/step is sufficient: all reads of
//    buffer (t&1) complete before the sync that precedes any write of step
//    t+2 into that same buffer.
//  - XCD-locality remap: bid = m*8 + rg*2 + b0 so (with round-robin
//    bid%8 -> XCD) each XCD hosts exactly one row-group; all 24 blocks of an
//    XCD read the SAME 196 KiB A-tile -> one L3 fill, then L2 hits.
// ---------------------------------------------------------------------------
__global__ __launch_bounds__(NTHR, 1) void gru_all(
    const unsigned short* __restrict__ wsw,
    unsigned short* hbase,
    const float* __restrict__ bias_ih, const float* __restrict__ bias_hh,
    const float* __restrict__ fc_w, float* __restrict__ ddot) {
  cg::grid_group grid = cg::this_grid();
  extern __shared__ char smem[];
  unsigned short* lds_w = (unsigned short*)smem;  // 144 chunks x 1 KiB

  const int bid = blockIdx.x;              // 0..191
  const int rg = (bid & 7) >> 1;           // XCD pair -> one row-group
  const int cb = ((bid >> 3) << 1) | (bid & 1);
  const int tid = threadIdx.x;
  const int lane = tid & 63;
  const int wave = tid >> 6;
  const int ln15 = lane & 15, quad = lane >> 4;

  // ---- async W staging, ONCE ----
  const unsigned short* wsrc = wsw + (size_t)cb * 73728;
  for (int i = 0; i < 36; ++i) {
    const int c = wave * 36 + i;
    __builtin_amdgcn_global_load_lds(
        (const __attribute__((address_space(1))) unsigned int*)(wsrc + (size_t)c * 512 + lane * 8),
        (__attribute__((address_space(3))) unsigned int*)(lds_w + (size_t)c * 512),
        16, 0, 0);
  }

  // ---- per-lane constants ----
  const int j = cb * 16 + ln15;
  const float bir = bias_ih[j], biz = bias_ih[Hn + j], bin = bias_ih[2 * Hn + j];
  const float bhr = bias_hh[j], bhz = bias_hh[Hn + j], bhn = bias_hh[2 * Hn + j];
  const float fw = fc_w[j];
  const int mrow0 = rg * 64 + wave * 16;  // wave's 16 rows
  const size_t N = (size_t)Bn * Hn;

  __syncthreads();  // drains vmcnt(0): W staging complete; W read-only after

  for (int t = 0; t < Tn; ++t) {
    const unsigned short* hhi_in = hbase + (size_t)(t & 1) * (2 * N);
    const unsigned short* hlo_in = hhi_in + N;
    unsigned short* hhi_out = hbase + (size_t)((t & 1) ^ 1) * (2 * N);
    unsigned short* hlo_out = hhi_out + N;

    // h_old loads (epilogue inputs) issued early; latency hidden by GEMM
    unsigned short hoh[4], hol[4];
#pragma unroll
    for (int i = 0; i < 4; ++i) {
      size_t idx = (size_t)(mrow0 + quad * 4 + i) * Hn + j;
      hoh[i] = hhi_in[idx];
      hol[i] = hlo_in[idx];
    }

    const unsigned short* Ah_base = hhi_in + (size_t)(mrow0 + ln15) * Hn + quad * 8;
    const unsigned short* Al_base = hlo_in + (size_t)(mrow0 + ln15) * Hn + quad * 8;

    floatx4 acc[3];
#pragma unroll
    for (int g = 0; g < 3; ++g) acc[g] = (floatx4){0.f, 0.f, 0.f, 0.f};

    short8 Abh[2][4], Abl[2][4];
#pragma unroll
    for (int q = 0; q < 4; ++q) {
      Abh[0][q] = *(const short8*)(Ah_base + q * 32);
      Abl[0][q] = *(const short8*)(Al_base + q * 32);
    }

#pragma unroll
    for (int c = 0; c < 6; ++c) {
      const int cur = c & 1, nxt = cur ^ 1;
      if (c < 5) {
#pragma unroll
        for (int q = 0; q < 4; ++q) {
          Abh[nxt][q] = *(const short8*)(Ah_base + ((c + 1) * 4 + q) * 32);
          Abl[nxt][q] = *(const short8*)(Al_base + ((c + 1) * 4 + q) * 32);
        }
      }
#pragma unroll
      for (int kk = 0; kk < 4; ++kk) {
        const int ks = c * 4 + kk;
#pragma unroll
        for (int g = 0; g < 3; ++g) {
          const int cbase = ((g * KS + ks) * 2) * 512 + lane * 8;
          short8 Bh = *(const short8*)(lds_w + cbase);
          short8 Bl = *(const short8*)(lds_w + cbase + 512);
          acc[g] = __builtin_amdgcn_mfma_f32_16x16x32_bf16(Abh[cur][kk], Bh, acc[g], 0, 0, 0);
          acc[g] = __builtin_amdgcn_mfma_f32_16x16x32_bf16(Abl[cur][kk], Bh, acc[g], 0, 0, 0);
          acc[g] = __builtin_amdgcn_mfma_f32_16x16x32_bf16(Abh[cur][kk], Bl, acc[g], 0, 0, 0);
        }
      }
    }

    // ---- epilogue: gates + h_new + fc partial (identical numerics) ----
    float fcv[4];
#pragma unroll
    for (int i = 0; i < 4; ++i) {
      const int r = mrow0 + quad * 4 + i;  // C/D layout: row = quad*4 + i
      float gr = bir + bhr + acc[0][i];
      float gz = biz + bhz + acc[1][i];
      float rr = 1.f / (1.f + __expf(-gr));
      float zz = 1.f / (1.f + __expf(-gz));
      float gn = bin + rr * (acc[2][i] + bhn);
      float nn = 1.f - 2.f / (1.f + __expf(2.f * gn));  // tanh
      float hold = bf2f(hoh[i]) + bf2f(hol[i]);
      float hn = (1.f - zz) * nn + zz * hold;
      size_t idx = (size_t)r * Hn + j;
      unsigned short hb = f2bf(hn);
      hhi_out[idx] = hb;
      hlo_out[idx] = f2bf(hn - bf2f(hb));
      fcv[i] = hn * fw;
    }
#pragma unroll
    for (int i = 0; i < 4; ++i) {
      fcv[i] += __shfl_xor(fcv[i], 1);
      fcv[i] += __shfl_xor(fcv[i], 2);
      fcv[i] += __shfl_xor(fcv[i], 4);
      fcv[i] += __shfl_xor(fcv[i], 8);
    }
    if (ln15 == 0) {
#pragma unroll
      for (int i = 0; i < 4; ++i)
        atomicAdd(&ddot[(size_t)t * Bn + mrow0 + quad * 4 + i], fcv[i]);
    }

    grid.sync();  // release(h stores -> L3) + barrier + acquire(invalidate)
  }
}

// ---------------------------------------------------------------------------
// Fallback: proven one-step-per-dispatch kernel (used only if cooperative
// launch is rejected). Unchanged from the previous verified version.
// ---------------------------------------------------------------------------
__global__ __launch_bounds__(NTHR) void gru_step(
    const unsigned short* __restrict__ wsw,
    const unsigned short* __restrict__ hhi_in,
    const unsigned short* __restrict__ hlo_in,
    unsigned short* __restrict__ hhi_out,
    unsigned short* __restrict__ hlo_out,
    const float* __restrict__ bias_ih, const float* __restrict__ bias_hh,
    const float* __restrict__ fc_w, float* __restrict__ ddot_t) {
  extern __shared__ char smem[];
  unsigned short* lds_w = (unsigned short*)smem;

  const int cb = blockIdx.x;
  const int rg = blockIdx.y;
  const int tid = threadIdx.x;
  const int lane = tid & 63;
  const int wave = tid >> 6;
  const int ln15 = lane & 15, quad = lane >> 4;
  const int j0 = cb * 16;

  const unsigned short* wsrc = wsw + (size_t)cb * 73728;
  for (int i = 0; i < 36; ++i) {
    const int c = wave * 36 + i;
    __builtin_amdgcn_global_load_lds(
        (const __attribute__((address_space(1))) unsigned int*)(wsrc + (size_t)c * 512 + lane * 8),
        (__attribute__((address_space(3))) unsigned int*)(lds_w + (size_t)c * 512),
        16, 0, 0);
  }

  const int j = j0 + ln15;
  const float bir = bias_ih[j], biz = bias_ih[Hn + j], bin = bias_ih[2 * Hn + j];
  const float bhr = bias_hh[j], bhz = bias_hh[Hn + j], bhn = bias_hh[2 * Hn + j];
  const float fw = fc_w[j];
  const int mrow0 = rg * 64 + wave * 16;

  unsigned short hoh[4], hol[4];
#pragma unroll
  for (int i = 0; i < 4; ++i) {
    size_t idx = (size_t)(mrow0 + quad * 4 + i) * Hn + j;
    hoh[i] = hhi_in[idx];
    hol[i] = hlo_in[idx];
  }

  const unsigned short* Ah_base = hhi_in + (size_t)(mrow0 + ln15) * Hn + quad * 8;
  const unsigned short* Al_base = hlo_in + (size_t)(mrow0 + ln15) * Hn + quad * 8;

  floatx4 acc[3];
#pragma unroll
  for (int g = 0; g < 3; ++g) acc[g] = (floatx4){0.f, 0.f, 0.f, 0.f};

  short8 Abh[2][4], Abl[2][4];
#pragma unroll
  for (int q = 0; q < 4; ++q) {
    Abh[0][q] = *(const short8*)(Ah_base + q * 32);
    Abl[0][q] = *(const short8*)(Al_base + q * 32);
  }

  __syncthreads();

#pragma unroll
  for (int c = 0; c < 6; ++c) {
    const int cur = c & 1, nxt = cur ^ 1;
    if (c < 5) {
#pragma unroll
      for (int q = 0; q < 4; ++q) {
        Abh[nxt][q] = *(const short8*)(Ah_base + ((c + 1) * 4 + q) * 32);
        Abl[nxt][q] = *(const short8*)(Al_base + ((c + 1) * 4 + q) * 32);
      }
    }
#pragma unroll
    for (int kk = 0; kk < 4; ++kk) {
      const int ks = c * 4 + kk;
#pragma unroll
      for (int g = 0; g < 3; ++g) {
        const int cbase = ((g * KS + ks) * 2) * 512 + lane * 8;
        short8 Bh = *(const short8*)(lds_w + cbase);
        short8 Bl = *(const short8*)(lds_w + cbase + 512);
        acc[g] = __builtin_amdgcn_mfma_f32_16x16x32_bf16(Abh[cur][kk], Bh, acc[g], 0, 0, 0);
        acc[g] = __builtin_amdgcn_mfma_f32_16x16x32_bf16(Abl[cur][kk], Bh, acc[g], 0, 0, 0);
        acc[g] = __builtin_amdgcn_mfma_f32_16x16x32_bf16(Abh[cur][kk], Bl, acc[g], 0, 0, 0);
      }
    }
  }

  float fcv[4];
#pragma unroll
  for (int i = 0; i < 4; ++i) {
    const int r = mrow0 + quad * 4 + i;
    float gr = bir + bhr + acc[0][i];
    float gz = biz + bhz + acc[1][i];
    float rr = 1.f / (1.f + __expf(-gr));
    float zz = 1.f / (1.f + __expf(-gz));
    float gn = bin + rr * (acc[2][i] + bhn);
    float nn = 1.f - 2.f / (1.f + __expf(2.f * gn));
    float hold = bf2f(hoh[i]) + bf2f(hol[i]);
    float hn = (1.f - zz) * nn + zz * hold;
    size_t idx = (size_t)r * Hn + j;
    unsigned short hb = f2bf(hn);
    hhi_out[idx] = hb;
    hlo_out[idx] = f2bf(hn - bf2f(hb));
    fcv[i] = hn * fw;
  }
#pragma unroll
  for (int i = 0; i < 4; ++i) {
    fcv[i] += __shfl_xor(fcv[i], 1);
    fcv[i] += __shfl_xor(fcv[i], 2);
    fcv[i] += __shfl_xor(fcv[i], 4);
    fcv[i] += __shfl_xor(fcv[i], 8);
  }
  if (ln15 == 0) {
#pragma unroll
    for (int i = 0; i < 4; ++i)
      atomicAdd(&ddot_t[mrow0 + quad * 4 + i], fcv[i]);
  }
}

// ---------------------------------------------------------------------------
// Post: softplus -> inclusive scan over T -> normalize -> assemble output.
// ---------------------------------------------------------------------------
__global__ void post_k(const float* __restrict__ ddot,
                       const float* __restrict__ fc_b,
                       const int* __restrict__ npred, float* __restrict__ out) {
  const int b = blockIdx.x;
  const int t = threadIdx.x;  // 0..127
  __shared__ float s[Tn];
  float x = ddot[(size_t)t * Bn + b] + fc_b[0];
  float sp = (x > 20.f) ? x : log1pf(__expf(x));
  s[t] = sp;
  __syncthreads();
  for (int off = 1; off < Tn; off <<= 1) {
    float v = s[t];
    float add = (t >= off) ? s[t - off] : 0.f;
    __syncthreads();
    s[t] = v + add;
    __syncthreads();
  }
  const int n = npred[b];
  const float last = s[n - 1] + 1e-6f;
  float body = (t < n) ? (s[t] / last) : 0.f;
  float* ob = out + (size_t)b * (Tn + 2);
  ob[1 + t] = body;
  if (t == 0) { ob[0] = 0.f; ob[Tn + 1] = 0.f; }
  __syncthreads();
  if (t == 0) ob[n + 1] = 1.f;
}

// ---------------------------------------------------------------------------
extern "C" void kernel_launch(void* const* d_in, const int* in_sizes, int n_in,
                              void* d_out, int out_size, void* d_ws, size_t ws_size,
                              hipStream_t stream) {
  const float* context   = (const float*)d_in[0];
  // d_in[1] = weight_ih: unused by the reference computation
  const float* weight_hh = (const float*)d_in[2];
  const float* bias_ih   = (const float*)d_in[3];
  const float* bias_hh   = (const float*)d_in[4];
  const float* fc_w      = (const float*)d_in[5];
  const float* fc_b      = (const float*)d_in[6];
  const int*   npred     = (const int*)d_in[7];
  float* out = (float*)d_out;

  char* ws = (char*)d_ws;
  size_t o = 0;
  unsigned short* hbase = (unsigned short*)(ws + o); o += (size_t)4 * Bn * Hn * 2;
  unsigned short* wsw   = (unsigned short*)(ws + o); o += (size_t)6 * Hn * Hn * 2;
  float* ddot = (float*)(ws + o); o += (size_t)Tn * Bn * 4;
  // ~8.8 MB of d_ws

  swz_w<<<dim3((2304 * (Hn / 8) + 255) / 256), dim3(256), 0, stream>>>(weight_hh, wsw);
  init_h<<<dim3((Bn * Hn + 255) / 256), dim3(256), 0, stream>>>(context, hbase, ddot);

  hipFuncSetAttribute((const void*)gru_all,
                      hipFuncAttributeMaxDynamicSharedMemorySize, SMEM_BYTES);

  const unsigned short* wsw_c = wsw;
  unsigned short* hb = hbase;
  const float* bih = bias_ih;
  const float* bhh = bias_hh;
  const float* fcw = fc_w;
  float* dd = ddot;
  void* args[] = {(void*)&wsw_c, (void*)&hb, (void*)&bih,
                  (void*)&bhh,  (void*)&fcw, (void*)&dd};
  hipError_t ce = hipLaunchCooperativeKernel((const void*)gru_all, dim3(NBLK),
                                             dim3(NTHR), args, SMEM_BYTES, stream);
  if (ce != hipSuccess) {
    // Fallback: proven per-step dispatch path (coherence via dispatch boundary)
    hipFuncSetAttribute((const void*)gru_step,
                        hipFuncAttributeMaxDynamicSharedMemorySize, SMEM_BYTES);
    const size_t N = (size_t)Bn * Hn;
    unsigned short* HHI[2] = {hbase, hbase + 2 * N};
    unsigned short* HLO[2] = {hbase + N, hbase + 3 * N};
    int cur = 0;
    for (int t = 0; t < Tn; ++t) {
      gru_step<<<dim3(CBn, RGn), dim3(NTHR), SMEM_BYTES, stream>>>(
          wsw, HHI[cur], HLO[cur], HHI[1 - cur], HLO[1 - cur],
          bias_ih, bias_hh, fc_w, ddot + (size_t)t * Bn);
      cur ^= 1;
    }
  }

  post_k<<<dim3(Bn), dim3(Tn), 0, stream>>>(ddot, fc_b, npred, out);
}

// Round 2
// 3038.535 us; speedup vs baseline: 1.2486x; 1.2486x over previous
//
#include <hip/hip_runtime.h>
#include <stdint.h>

// Problem constants (fixed by setup_inputs)
#define Bn 256
#define Hn 768
#define Tn 128
#define KS 24      // Hn/32 ksteps
#define CBn 48     // col-blocks (j-tiles of 16 hidden units x 3 gates)
#define RGn 4      // row-groups of 64 batch rows
#define NTHR 256   // 4 waves; wave w owns m-tile w (16 rows), all gates, full K
#define NBLK 192   // CBn * RGn
#define SMEM_BYTES 147456  // W slice hi+lo in LDS (dynamic)

typedef __attribute__((ext_vector_type(8))) short short8;   // 8 bf16
typedef __attribute__((ext_vector_type(4))) float floatx4;  // mfma C/D

static __device__ __forceinline__ unsigned short f2bf(float f) {
  unsigned int x = __float_as_uint(f);
  x += 0x7fffu + ((x >> 16) & 1u);
  return (unsigned short)(x >> 16);
}
static __device__ __forceinline__ float bf2f(unsigned short u) {
  return __uint_as_float(((unsigned int)u) << 16);
}

// ---------------------------------------------------------------------------
// Swizzle W_hh (2304x768 fp32 row-major) into slice-contiguous B-fragment
// order, bf16 hi/lo interleaved per chunk (unchanged).
// ---------------------------------------------------------------------------
__global__ void swz_w(const float* __restrict__ W,
                      unsigned short* __restrict__ wsw) {
  int i = blockIdx.x * blockDim.x + threadIdx.x;
  if (i >= 2304 * (Hn / 8)) return;
  int n  = i / (Hn / 8);
  int k0 = (i % (Hn / 8)) * 8;
  int g = n / Hn, jj = n % Hn;
  int cb = jj >> 4, l15 = jj & 15;
  int ks = k0 >> 5, k8 = (k0 >> 3) & 3;
  int lane = l15 + 16 * k8;
  unsigned short* slice = wsw + (size_t)cb * 73728;
  size_t offh = ((size_t)((g * KS + ks) * 2 + 0)) * 512 + (size_t)lane * 8;
  size_t offl = ((size_t)((g * KS + ks) * 2 + 1)) * 512 + (size_t)lane * 8;
  const float* src = W + (size_t)n * Hn + k0;
  short8 h8, l8;
#pragma unroll
  for (int q = 0; q < 8; ++q) {
    float w = src[q];
    unsigned short hb = f2bf(w);
    h8[q] = (short)hb;
    l8[q] = (short)f2bf(w - bf2f(hb));
  }
  *(short8*)(slice + offh) = h8;
  *(short8*)(slice + offl) = l8;
}

// ---------------------------------------------------------------------------
// Init: h0 planes (bf16 hi/lo) from context; zero ddot; zero barrier counter.
// hbase layout: [hhi0 | hlo0 | hhi1 | hlo1], each Bn*Hn elements.
// ---------------------------------------------------------------------------
__global__ void init_h(const float* __restrict__ ctx,
                       unsigned short* __restrict__ hbase,
                       float* __restrict__ ddot, int* __restrict__ bar) {
  int i = blockIdx.x * blockDim.x + threadIdx.x;
  if (i < Bn * Hn) {
    float c = ctx[i];
    unsigned short hb = f2bf(c);
    hbase[i] = hb;                            // hhi0
    hbase[Bn * Hn + i] = f2bf(c - bf2f(hb));  // hlo0
  }
  if (i < Tn * Bn) ddot[i] = 0.f;
  if (i == 0) *bar = 0;
}

// ---------------------------------------------------------------------------
// PERSISTENT cooperative kernel, custom lightweight barrier.
//  - h stores are agent-scope relaxed atomics (global_store_dword sc1):
//    write-through to L3, no dirty L2 => the step barrier needs NO buffer_wbl2
//    (that writeback was ~25us/step inside grid.sync()).
//  - Barrier: __syncthreads() drains each thread's vmcnt (sc1 stores acked at
//    L3), tid0 does relaxed agent fetch_add on a MONOTONE counter and spins
//    until count >= NBLK*(t+1). Monotone => no reset race; double-buffered h
//    => one barrier/step suffices (arrival happens after the block's reads of
//    the old buffer completed, so a fast block can't overwrite a buffer a slow
//    block is still reading).
//  - Acquire: __builtin_amdgcn_fence(ACQUIRE,"agent") = flash invalidate only.
//    Next step's A-loads stay NORMAL vectorized b128, refilled from L3 once
//    per XCD (rg <-> XCD-pair affinity => 24 blocks/XCD share one A-tile).
// ---------------------------------------------------------------------------
__global__ __launch_bounds__(NTHR, 1) void gru_all(
    const unsigned short* __restrict__ wsw,
    unsigned short* hbase,
    const float* __restrict__ bias_ih, const float* __restrict__ bias_hh,
    const float* __restrict__ fc_w, float* __restrict__ ddot,
    int* bar) {
  extern __shared__ char smem[];
  unsigned short* lds_w = (unsigned short*)smem;  // 144 chunks x 1 KiB

  const int bid = blockIdx.x;              // 0..191
  const int rg = (bid & 7) >> 1;           // XCD pair -> one row-group
  const int cb = ((bid >> 3) << 1) | (bid & 1);
  const int tid = threadIdx.x;
  const int lane = tid & 63;
  const int wave = tid >> 6;
  const int ln15 = lane & 15, quad = lane >> 4;

  // ---- async W staging, ONCE ----
  const unsigned short* wsrc = wsw + (size_t)cb * 73728;
  for (int i = 0; i < 36; ++i) {
    const int c = wave * 36 + i;
    __builtin_amdgcn_global_load_lds(
        (const __attribute__((address_space(1))) unsigned int*)(wsrc + (size_t)c * 512 + lane * 8),
        (__attribute__((address_space(3))) unsigned int*)(lds_w + (size_t)c * 512),
        16, 0, 0);
  }

  // ---- per-lane constants ----
  const int j = cb * 16 + ln15;
  const float bir = bias_ih[j], biz = bias_ih[Hn + j], bin = bias_ih[2 * Hn + j];
  const float bhr = bias_hh[j], bhz = bias_hh[Hn + j], bhn = bias_hh[2 * Hn + j];
  const float fw = fc_w[j];
  const int mrow0 = rg * 64 + wave * 16;  // wave's 16 rows
  const size_t N = (size_t)Bn * Hn;
  const bool evenlane = ((ln15 & 1) == 0);

  __syncthreads();  // drains vmcnt(0): W staging complete; W read-only after

  for (int t = 0; t < Tn; ++t) {
    const unsigned short* hhi_in = hbase + (size_t)(t & 1) * (2 * N);
    const unsigned short* hlo_in = hhi_in + N;
    unsigned short* hhi_out = hbase + (size_t)((t & 1) ^ 1) * (2 * N);
    unsigned short* hlo_out = hhi_out + N;

    // h_old loads (epilogue inputs) issued early; latency hidden by GEMM
    unsigned short hoh[4], hol[4];
#pragma unroll
    for (int i = 0; i < 4; ++i) {
      size_t idx = (size_t)(mrow0 + quad * 4 + i) * Hn + j;
      hoh[i] = hhi_in[idx];
      hol[i] = hlo_in[idx];
    }

    const unsigned short* Ah_base = hhi_in + (size_t)(mrow0 + ln15) * Hn + quad * 8;
    const unsigned short* Al_base = hlo_in + (size_t)(mrow0 + ln15) * Hn + quad * 8;

    floatx4 acc[3];
#pragma unroll
    for (int g = 0; g < 3; ++g) acc[g] = (floatx4){0.f, 0.f, 0.f, 0.f};

    short8 Abh[2][4], Abl[2][4];
#pragma unroll
    for (int q = 0; q < 4; ++q) {
      Abh[0][q] = *(const short8*)(Ah_base + q * 32);
      Abl[0][q] = *(const short8*)(Al_base + q * 32);
    }

#pragma unroll
    for (int c = 0; c < 6; ++c) {
      const int cur = c & 1, nxt = cur ^ 1;
      if (c < 5) {
#pragma unroll
        for (int q = 0; q < 4; ++q) {
          Abh[nxt][q] = *(const short8*)(Ah_base + ((c + 1) * 4 + q) * 32);
          Abl[nxt][q] = *(const short8*)(Al_base + ((c + 1) * 4 + q) * 32);
        }
      }
#pragma unroll
      for (int kk = 0; kk < 4; ++kk) {
        const int ks = c * 4 + kk;
#pragma unroll
        for (int g = 0; g < 3; ++g) {
          const int cbase = ((g * KS + ks) * 2) * 512 + lane * 8;
          short8 Bh = *(const short8*)(lds_w + cbase);
          short8 Bl = *(const short8*)(lds_w + cbase + 512);
          acc[g] = __builtin_amdgcn_mfma_f32_16x16x32_bf16(Abh[cur][kk], Bh, acc[g], 0, 0, 0);
          acc[g] = __builtin_amdgcn_mfma_f32_16x16x32_bf16(Abl[cur][kk], Bh, acc[g], 0, 0, 0);
          acc[g] = __builtin_amdgcn_mfma_f32_16x16x32_bf16(Abh[cur][kk], Bl, acc[g], 0, 0, 0);
        }
      }
    }

    // ---- epilogue: gates + h_new + fc partial (identical numerics) ----
    float fcv[4];
    unsigned int ph[4], pl[4];
#pragma unroll
    for (int i = 0; i < 4; ++i) {
      float gr = bir + bhr + acc[0][i];
      float gz = biz + bhz + acc[1][i];
      float rr = 1.f / (1.f + __expf(-gr));
      float zz = 1.f / (1.f + __expf(-gz));
      float gn = bin + rr * (acc[2][i] + bhn);
      float nn = 1.f - 2.f / (1.f + __expf(2.f * gn));  // tanh
      float hold = bf2f(hoh[i]) + bf2f(hol[i]);
      float hn = (1.f - zz) * nn + zz * hold;
      unsigned short hb = f2bf(hn);
      ph[i] = (unsigned int)hb;
      pl[i] = (unsigned int)f2bf(hn - bf2f(hb));
      fcv[i] = hn * fw;
    }
    // pack adjacent-j pairs (lane^1 holds j^1; same rows) -> dword sc1 stores
#pragma unroll
    for (int i = 0; i < 4; ++i) {
      unsigned int oh = (unsigned int)__shfl_xor((int)ph[i], 1);
      unsigned int ol = (unsigned int)__shfl_xor((int)pl[i], 1);
      if (evenlane) {
        size_t idx = (size_t)(mrow0 + quad * 4 + i) * Hn + j;  // j even
        __hip_atomic_store((unsigned int*)(hhi_out + idx), ph[i] | (oh << 16),
                           __ATOMIC_RELAXED, __HIP_MEMORY_SCOPE_AGENT);
        __hip_atomic_store((unsigned int*)(hlo_out + idx), pl[i] | (ol << 16),
                           __ATOMIC_RELAXED, __HIP_MEMORY_SCOPE_AGENT);
      }
    }
#pragma unroll
    for (int i = 0; i < 4; ++i) {
      fcv[i] += __shfl_xor(fcv[i], 1);
      fcv[i] += __shfl_xor(fcv[i], 2);
      fcv[i] += __shfl_xor(fcv[i], 4);
      fcv[i] += __shfl_xor(fcv[i], 8);
    }
    if (ln15 == 0) {
#pragma unroll
      for (int i = 0; i < 4; ++i)
        atomicAdd(&ddot[(size_t)t * Bn + mrow0 + quad * 4 + i], fcv[i]);
    }

    // ---- lightweight device barrier (skip after last step) ----
    if (t < Tn - 1) {
      asm volatile("s_waitcnt vmcnt(0)" ::: "memory");  // sc1 stores at L3
      __syncthreads();  // all threads of block drained & arrived
      if (tid == 0) {
        __hip_atomic_fetch_add(bar, 1, __ATOMIC_RELAXED, __HIP_MEMORY_SCOPE_AGENT);
        const int target = NBLK * (t + 1);
        while (__hip_atomic_load(bar, __ATOMIC_RELAXED, __HIP_MEMORY_SCOPE_AGENT) < target)
          __builtin_amdgcn_s_sleep(1);
      }
      __syncthreads();
      // flash-invalidate L1/L2 so normal b128 loads see the sc1 data in L3
      __builtin_amdgcn_fence(__ATOMIC_ACQUIRE, "agent");
    }
  }
}

// ---------------------------------------------------------------------------
// Fallback: proven one-step-per-dispatch kernel (used only if cooperative
// launch is rejected). Unchanged from the verified 1944us version.
// ---------------------------------------------------------------------------
__global__ __launch_bounds__(NTHR) void gru_step(
    const unsigned short* __restrict__ wsw,
    const unsigned short* __restrict__ hhi_in,
    const unsigned short* __restrict__ hlo_in,
    unsigned short* __restrict__ hhi_out,
    unsigned short* __restrict__ hlo_out,
    const float* __restrict__ bias_ih, const float* __restrict__ bias_hh,
    const float* __restrict__ fc_w, float* __restrict__ ddot_t) {
  extern __shared__ char smem[];
  unsigned short* lds_w = (unsigned short*)smem;

  const int cb = blockIdx.x;
  const int rg = blockIdx.y;
  const int tid = threadIdx.x;
  const int lane = tid & 63;
  const int wave = tid >> 6;
  const int ln15 = lane & 15, quad = lane >> 4;
  const int j0 = cb * 16;

  const unsigned short* wsrc = wsw + (size_t)cb * 73728;
  for (int i = 0; i < 36; ++i) {
    const int c = wave * 36 + i;
    __builtin_amdgcn_global_load_lds(
        (const __attribute__((address_space(1))) unsigned int*)(wsrc + (size_t)c * 512 + lane * 8),
        (__attribute__((address_space(3))) unsigned int*)(lds_w + (size_t)c * 512),
        16, 0, 0);
  }

  const int j = j0 + ln15;
  const float bir = bias_ih[j], biz = bias_ih[Hn + j], bin = bias_ih[2 * Hn + j];
  const float bhr = bias_hh[j], bhz = bias_hh[Hn + j], bhn = bias_hh[2 * Hn + j];
  const float fw = fc_w[j];
  const int mrow0 = rg * 64 + wave * 16;

  unsigned short hoh[4], hol[4];
#pragma unroll
  for (int i = 0; i < 4; ++i) {
    size_t idx = (size_t)(mrow0 + quad * 4 + i) * Hn + j;
    hoh[i] = hhi_in[idx];
    hol[i] = hlo_in[idx];
  }

  const unsigned short* Ah_base = hhi_in + (size_t)(mrow0 + ln15) * Hn + quad * 8;
  const unsigned short* Al_base = hlo_in + (size_t)(mrow0 + ln15) * Hn + quad * 8;

  floatx4 acc[3];
#pragma unroll
  for (int g = 0; g < 3; ++g) acc[g] = (floatx4){0.f, 0.f, 0.f, 0.f};

  short8 Abh[2][4], Abl[2][4];
#pragma unroll
  for (int q = 0; q < 4; ++q) {
    Abh[0][q] = *(const short8*)(Ah_base + q * 32);
    Abl[0][q] = *(const short8*)(Al_base + q * 32);
  }

  __syncthreads();

#pragma unroll
  for (int c = 0; c < 6; ++c) {
    const int cur = c & 1, nxt = cur ^ 1;
    if (c < 5) {
#pragma unroll
      for (int q = 0; q < 4; ++q) {
        Abh[nxt][q] = *(const short8*)(Ah_base + ((c + 1) * 4 + q) * 32);
        Abl[nxt][q] = *(const short8*)(Al_base + ((c + 1) * 4 + q) * 32);
      }
    }
#pragma unroll
    for (int kk = 0; kk < 4; ++kk) {
      const int ks = c * 4 + kk;
#pragma unroll
      for (int g = 0; g < 3; ++g) {
        const int cbase = ((g * KS + ks) * 2) * 512 + lane * 8;
        short8 Bh = *(const short8*)(lds_w + cbase);
        short8 Bl = *(const short8*)(lds_w + cbase + 512);
        acc[g] = __builtin_amdgcn_mfma_f32_16x16x32_bf16(Abh[cur][kk], Bh, acc[g], 0, 0, 0);
        acc[g] = __builtin_amdgcn_mfma_f32_16x16x32_bf16(Abl[cur][kk], Bh, acc[g], 0, 0, 0);
        acc[g] = __builtin_amdgcn_mfma_f32_16x16x32_bf16(Abh[cur][kk], Bl, acc[g], 0, 0, 0);
      }
    }
  }

  float fcv[4];
#pragma unroll
  for (int i = 0; i < 4; ++i) {
    const int r = mrow0 + quad * 4 + i;
    float gr = bir + bhr + acc[0][i];
    float gz = biz + bhz + acc[1][i];
    float rr = 1.f / (1.f + __expf(-gr));
    float zz = 1.f / (1.f + __expf(-gz));
    float gn = bin + rr * (acc[2][i] + bhn);
    float nn = 1.f - 2.f / (1.f + __expf(2.f * gn));
    float hold = bf2f(hoh[i]) + bf2f(hol[i]);
    float hn = (1.f - zz) * nn + zz * hold;
    size_t idx = (size_t)r * Hn + j;
    unsigned short hb = f2bf(hn);
    hhi_out[idx] = hb;
    hlo_out[idx] = f2bf(hn - bf2f(hb));
    fcv[i] = hn * fw;
  }
#pragma unroll
  for (int i = 0; i < 4; ++i) {
    fcv[i] += __shfl_xor(fcv[i], 1);
    fcv[i] += __shfl_xor(fcv[i], 2);
    fcv[i] += __shfl_xor(fcv[i], 4);
    fcv[i] += __shfl_xor(fcv[i], 8);
  }
  if (ln15 == 0) {
#pragma unroll
    for (int i = 0; i < 4; ++i)
      atomicAdd(&ddot_t[mrow0 + quad * 4 + i], fcv[i]);
  }
}

// ---------------------------------------------------------------------------
// Post: softplus -> inclusive scan over T -> normalize -> assemble output.
// ---------------------------------------------------------------------------
__global__ void post_k(const float* __restrict__ ddot,
                       const float* __restrict__ fc_b,
                       const int* __restrict__ npred, float* __restrict__ out) {
  const int b = blockIdx.x;
  const int t = threadIdx.x;  // 0..127
  __shared__ float s[Tn];
  float x = ddot[(size_t)t * Bn + b] + fc_b[0];
  float sp = (x > 20.f) ? x : log1pf(__expf(x));
  s[t] = sp;
  __syncthreads();
  for (int off = 1; off < Tn; off <<= 1) {
    float v = s[t];
    float add = (t >= off) ? s[t - off] : 0.f;
    __syncthreads();
    s[t] = v + add;
    __syncthreads();
  }
  const int n = npred[b];
  const float last = s[n - 1] + 1e-6f;
  float body = (t < n) ? (s[t] / last) : 0.f;
  float* ob = out + (size_t)b * (Tn + 2);
  ob[1 + t] = body;
  if (t == 0) { ob[0] = 0.f; ob[Tn + 1] = 0.f; }
  __syncthreads();
  if (t == 0) ob[n + 1] = 1.f;
}

// ---------------------------------------------------------------------------
extern "C" void kernel_launch(void* const* d_in, const int* in_sizes, int n_in,
                              void* d_out, int out_size, void* d_ws, size_t ws_size,
                              hipStream_t stream) {
  const float* context   = (const float*)d_in[0];
  // d_in[1] = weight_ih: unused by the reference computation
  const float* weight_hh = (const float*)d_in[2];
  const float* bias_ih   = (const float*)d_in[3];
  const float* bias_hh   = (const float*)d_in[4];
  const float* fc_w      = (const float*)d_in[5];
  const float* fc_b      = (const float*)d_in[6];
  const int*   npred     = (const int*)d_in[7];
  float* out = (float*)d_out;

  char* ws = (char*)d_ws;
  size_t o = 0;
  unsigned short* hbase = (unsigned short*)(ws + o); o += (size_t)4 * Bn * Hn * 2;
  unsigned short* wsw   = (unsigned short*)(ws + o); o += (size_t)6 * Hn * Hn * 2;
  float* ddot = (float*)(ws + o); o += (size_t)Tn * Bn * 4;
  int* bar = (int*)(ws + o); o += 64;
  // ~8.8 MB of d_ws

  swz_w<<<dim3((2304 * (Hn / 8) + 255) / 256), dim3(256), 0, stream>>>(weight_hh, wsw);
  init_h<<<dim3((Bn * Hn + 255) / 256), dim3(256), 0, stream>>>(context, hbase, ddot, bar);

  hipFuncSetAttribute((const void*)gru_all,
                      hipFuncAttributeMaxDynamicSharedMemorySize, SMEM_BYTES);

  const unsigned short* wsw_c = wsw;
  unsigned short* hb = hbase;
  const float* bih = bias_ih;
  const float* bhh = bias_hh;
  const float* fcw = fc_w;
  float* dd = ddot;
  int* bp = bar;
  void* args[] = {(void*)&wsw_c, (void*)&hb, (void*)&bih,
                  (void*)&bhh,  (void*)&fcw, (void*)&dd, (void*)&bp};
  hipError_t ce = hipLaunchCooperativeKernel((const void*)gru_all, dim3(NBLK),
                                             dim3(NTHR), args, SMEM_BYTES, stream);
  if (ce != hipSuccess) {
    // Fallback: proven per-step dispatch path (coherence via dispatch boundary)
    hipFuncSetAttribute((const void*)gru_step,
                        hipFuncAttributeMaxDynamicSharedMemorySize, SMEM_BYTES);
    const size_t N = (size_t)Bn * Hn;
    unsigned short* HHI[2] = {hbase, hbase + 2 * N};
    unsigned short* HLO[2] = {hbase + N, hbase + 3 * N};
    int cur = 0;
    for (int t = 0; t < Tn; ++t) {
      gru_step<<<dim3(CBn, RGn), dim3(NTHR), SMEM_BYTES, stream>>>(
          wsw, HHI[cur], HLO[cur], HHI[1 - cur], HLO[1 - cur],
          bias_ih, bias_hh, fc_w, ddot + (size_t)t * Bn);
      cur ^= 1;
    }
  }

  post_k<<<dim3(Bn), dim3(Tn), 0, stream>>>(ddot, fc_b, npred, out);
}

// Round 3
// 2454.080 us; speedup vs baseline: 1.5460x; 1.2382x over previous
//
#include <hip/hip_runtime.h>
#include <stdint.h>

// Problem constants (fixed by setup_inputs)
#define Bn 256
#define Hn 768
#define Tn 128
#define KS 24      // Hn/32 ksteps
#define CBn 48     // col-blocks (j-tiles of 16 hidden units x 3 gates)
#define RGn 4      // row-groups of 64 batch rows
#define NTHR 256   // 4 waves; wave w owns m-tile w (16 rows), all gates, full K
#define NBLK 192   // CBn * RGn
#define SMEM_BYTES 147456  // W slice hi+lo in LDS (dynamic)

typedef __attribute__((ext_vector_type(8))) short short8;   // 8 bf16
typedef __attribute__((ext_vector_type(4))) float floatx4;  // mfma C/D

static __device__ __forceinline__ unsigned short f2bf(float f) {
  unsigned int x = __float_as_uint(f);
  x += 0x7fffu + ((x >> 16) & 1u);
  return (unsigned short)(x >> 16);
}
static __device__ __forceinline__ float bf2f(unsigned short u) {
  return __uint_as_float(((unsigned int)u) << 16);
}

// ---------------------------------------------------------------------------
// Swizzle W_hh (2304x768 fp32 row-major) into slice-contiguous B-fragment
// order, bf16 hi/lo interleaved per chunk (unchanged).
// ---------------------------------------------------------------------------
__global__ void swz_w(const float* __restrict__ W,
                      unsigned short* __restrict__ wsw) {
  int i = blockIdx.x * blockDim.x + threadIdx.x;
  if (i >= 2304 * (Hn / 8)) return;
  int n  = i / (Hn / 8);
  int k0 = (i % (Hn / 8)) * 8;
  int g = n / Hn, jj = n % Hn;
  int cb = jj >> 4, l15 = jj & 15;
  int ks = k0 >> 5, k8 = (k0 >> 3) & 3;
  int lane = l15 + 16 * k8;
  unsigned short* slice = wsw + (size_t)cb * 73728;
  size_t offh = ((size_t)((g * KS + ks) * 2 + 0)) * 512 + (size_t)lane * 8;
  size_t offl = ((size_t)((g * KS + ks) * 2 + 1)) * 512 + (size_t)lane * 8;
  const float* src = W + (size_t)n * Hn + k0;
  short8 h8, l8;
#pragma unroll
  for (int q = 0; q < 8; ++q) {
    float w = src[q];
    unsigned short hb = f2bf(w);
    h8[q] = (short)hb;
    l8[q] = (short)f2bf(w - bf2f(hb));
  }
  *(short8*)(slice + offh) = h8;
  *(short8*)(slice + offl) = l8;
}

// ---------------------------------------------------------------------------
// Init: h0 planes (bf16 hi/lo) from context; zero ddot; zero barrier flags.
// hbase layout: [hhi0 | hlo0 | hhi1 | hlo1], each Bn*Hn elements.
// ---------------------------------------------------------------------------
__global__ void init_h(const float* __restrict__ ctx,
                       unsigned short* __restrict__ hbase,
                       float* __restrict__ ddot, int* __restrict__ flags) {
  int i = blockIdx.x * blockDim.x + threadIdx.x;
  if (i < Bn * Hn) {
    float c = ctx[i];
    unsigned short hb = f2bf(c);
    hbase[i] = hb;                            // hhi0
    hbase[Bn * Hn + i] = f2bf(c - bf2f(hb));  // hlo0
  }
  if (i < Tn * Bn) ddot[i] = 0.f;
  if (i < RGn * 128) flags[i] = 0;
}

// ---------------------------------------------------------------------------
// PERSISTENT cooperative kernel, contention-free per-rg flag barrier.
//  - h stores: agent-scope relaxed atomics (sc1 write-through, no dirty L2).
//  - Arrive: each wave drains its vmcnt (h stores acked at L3), block syncs,
//    tid0 STORES epoch t+1 to the block's OWN flag dword (48 parallel stores
//    to distinct addresses -- no RMW serialization; r2's single fetch_add
//    counter serialized 192 RMWs at one L3 slice = the ~15us/step hotspot).
//  - Wait: wave0 lane l polls flag[l] of its rg (3 cache lines, read-only),
//    __all(v >= t+1) detects in ~1 L3 round trip.
//  - Per-rg (48 blocks): consumers of h[rg] are exactly the 48 same-rg
//    blocks; rgs are fully independent (disjoint rows, disjoint ddot rows).
//  - Acquire: fence(acquire, agent) = flash invalidate; then ALL 6 A-chunks
//    (48 b128 loads) issue up-front: 1 wave/SIMD has no TLP to hide L3
//    latency, so full prefetch collapses the chain to ~1 latency.
//  - ddot atomics issued AFTER the barrier (consumed only by post_k) so their
//    per-address serialization overlaps the next step's load phase.
// ---------------------------------------------------------------------------
__global__ __launch_bounds__(NTHR, 1) void gru_all(
    const unsigned short* __restrict__ wsw,
    unsigned short* hbase,
    const float* __restrict__ bias_ih, const float* __restrict__ bias_hh,
    const float* __restrict__ fc_w, float* __restrict__ ddot,
    int* flags) {
  extern __shared__ char smem[];
  unsigned short* lds_w = (unsigned short*)smem;  // 144 chunks x 1 KiB

  const int bid = blockIdx.x;              // 0..191
  const int rg = (bid & 7) >> 1;           // XCD pair -> one row-group
  const int cb = ((bid >> 3) << 1) | (bid & 1);
  const int tid = threadIdx.x;
  const int lane = tid & 63;
  const int wave = tid >> 6;
  const int ln15 = lane & 15, quad = lane >> 4;

  // ---- async W staging, ONCE ----
  const unsigned short* wsrc = wsw + (size_t)cb * 73728;
  for (int i = 0; i < 36; ++i) {
    const int c = wave * 36 + i;
    __builtin_amdgcn_global_load_lds(
        (const __attribute__((address_space(1))) unsigned int*)(wsrc + (size_t)c * 512 + lane * 8),
        (__attribute__((address_space(3))) unsigned int*)(lds_w + (size_t)c * 512),
        16, 0, 0);
  }

  // ---- per-lane constants ----
  const int j = cb * 16 + ln15;
  const float bir = bias_ih[j], biz = bias_ih[Hn + j], bin = bias_ih[2 * Hn + j];
  const float bhr = bias_hh[j], bhz = bias_hh[Hn + j], bhn = bias_hh[2 * Hn + j];
  const float fw = fc_w[j];
  const int mrow0 = rg * 64 + wave * 16;  // wave's 16 rows
  const size_t N = (size_t)Bn * Hn;
  const bool evenlane = ((ln15 & 1) == 0);
  int* const myflag = flags + rg * 128 + cb;
  int* const pollp  = flags + rg * 128 + ((lane < CBn) ? lane : (CBn - 1));

  __syncthreads();  // drains vmcnt(0): W staging complete; W read-only after

  float fcv[4];
  bool have_fc = false;
  int fc_t = 0, fc_r0 = 0;

  for (int t = 0; t < Tn; ++t) {
    const unsigned short* hhi_in = hbase + (size_t)(t & 1) * (2 * N);
    const unsigned short* hlo_in = hhi_in + N;
    unsigned short* hhi_out = hbase + (size_t)((t & 1) ^ 1) * (2 * N);
    unsigned short* hlo_out = hhi_out + N;

    const unsigned short* Ah_base = hhi_in + (size_t)(mrow0 + ln15) * Hn + quad * 8;
    const unsigned short* Al_base = hlo_in + (size_t)(mrow0 + ln15) * Hn + quad * 8;

    // ---- FULL A prefetch: all 6 chunks (48 b128 loads) issued up-front ----
    short8 Abh[6][4], Abl[6][4];
#pragma unroll
    for (int c = 0; c < 6; ++c) {
#pragma unroll
      for (int q = 0; q < 4; ++q) {
        Abh[c][q] = *(const short8*)(Ah_base + (c * 4 + q) * 32);
        Abl[c][q] = *(const short8*)(Al_base + (c * 4 + q) * 32);
      }
    }

    // h_old loads (epilogue inputs) -- issued after A (needed later)
    unsigned short hoh[4], hol[4];
#pragma unroll
    for (int i = 0; i < 4; ++i) {
      size_t idx = (size_t)(mrow0 + quad * 4 + i) * Hn + j;
      hoh[i] = hhi_in[idx];
      hol[i] = hlo_in[idx];
    }

    // deferred ddot atomics from previous step (overlap with A-load latency)
    if (have_fc) {
      if (ln15 == 0) {
#pragma unroll
        for (int i = 0; i < 4; ++i)
          atomicAdd(&ddot[(size_t)fc_t * Bn + fc_r0 + i], fcv[i]);
      }
      have_fc = false;
    }

    floatx4 acc[3];
#pragma unroll
    for (int g = 0; g < 3; ++g) acc[g] = (floatx4){0.f, 0.f, 0.f, 0.f};

#pragma unroll
    for (int c = 0; c < 6; ++c) {
#pragma unroll
      for (int kk = 0; kk < 4; ++kk) {
        const int ks = c * 4 + kk;
#pragma unroll
        for (int g = 0; g < 3; ++g) {
          const int cbase = ((g * KS + ks) * 2) * 512 + lane * 8;
          short8 Bh = *(const short8*)(lds_w + cbase);
          short8 Bl = *(const short8*)(lds_w + cbase + 512);
          acc[g] = __builtin_amdgcn_mfma_f32_16x16x32_bf16(Abh[c][kk], Bh, acc[g], 0, 0, 0);
          acc[g] = __builtin_amdgcn_mfma_f32_16x16x32_bf16(Abl[c][kk], Bh, acc[g], 0, 0, 0);
          acc[g] = __builtin_amdgcn_mfma_f32_16x16x32_bf16(Abh[c][kk], Bl, acc[g], 0, 0, 0);
        }
      }
    }

    // ---- epilogue: gates + h_new + fc partial (identical numerics) ----
    unsigned int ph[4], pl[4];
#pragma unroll
    for (int i = 0; i < 4; ++i) {
      float gr = bir + bhr + acc[0][i];
      float gz = biz + bhz + acc[1][i];
      float rr = 1.f / (1.f + __expf(-gr));
      float zz = 1.f / (1.f + __expf(-gz));
      float gn = bin + rr * (acc[2][i] + bhn);
      float nn = 1.f - 2.f / (1.f + __expf(2.f * gn));  // tanh
      float hold = bf2f(hoh[i]) + bf2f(hol[i]);
      float hn = (1.f - zz) * nn + zz * hold;
      unsigned short hb = f2bf(hn);
      ph[i] = (unsigned int)hb;
      pl[i] = (unsigned int)f2bf(hn - bf2f(hb));
      fcv[i] = hn * fw;
    }
    // pack adjacent-j pairs (lane^1 holds j^1; same rows) -> dword sc1 stores
#pragma unroll
    for (int i = 0; i < 4; ++i) {
      unsigned int oh = (unsigned int)__shfl_xor((int)ph[i], 1);
      unsigned int ol = (unsigned int)__shfl_xor((int)pl[i], 1);
      if (evenlane) {
        size_t idx = (size_t)(mrow0 + quad * 4 + i) * Hn + j;  // j even
        __hip_atomic_store((unsigned int*)(hhi_out + idx), ph[i] | (oh << 16),
                           __ATOMIC_RELAXED, __HIP_MEMORY_SCOPE_AGENT);
        __hip_atomic_store((unsigned int*)(hlo_out + idx), pl[i] | (ol << 16),
                           __ATOMIC_RELAXED, __HIP_MEMORY_SCOPE_AGENT);
      }
    }
    // fc partial reduce in-register (atomics deferred past the barrier)
#pragma unroll
    for (int i = 0; i < 4; ++i) {
      fcv[i] += __shfl_xor(fcv[i], 1);
      fcv[i] += __shfl_xor(fcv[i], 2);
      fcv[i] += __shfl_xor(fcv[i], 4);
      fcv[i] += __shfl_xor(fcv[i], 8);
    }
    have_fc = true;
    fc_t = t;
    fc_r0 = mrow0 + quad * 4;

    // ---- per-rg flag barrier (skip after last step) ----
    if (t < Tn - 1) {
      asm volatile("s_waitcnt vmcnt(0)" ::: "memory");  // h stores acked at L3
      __syncthreads();                                  // whole block drained
      if (tid == 0)
        __hip_atomic_store(myflag, t + 1, __ATOMIC_RELAXED,
                           __HIP_MEMORY_SCOPE_AGENT);   // own slot: no RMW
      if (wave == 0) {
        for (;;) {
          int v = __hip_atomic_load(pollp, __ATOMIC_RELAXED,
                                    __HIP_MEMORY_SCOPE_AGENT);
          if (__all(v >= t + 1)) break;
          __builtin_amdgcn_s_sleep(1);
        }
      }
      __syncthreads();
      // flash-invalidate stale L1/L2 h lines; loads then refill from L3
      __builtin_amdgcn_fence(__ATOMIC_ACQUIRE, "agent");
    }
  }

  // last step's ddot contribution
  if (ln15 == 0) {
#pragma unroll
    for (int i = 0; i < 4; ++i)
      atomicAdd(&ddot[(size_t)fc_t * Bn + fc_r0 + i], fcv[i]);
  }
}

// ---------------------------------------------------------------------------
// Fallback: proven one-step-per-dispatch kernel (used only if cooperative
// launch is rejected). Unchanged from the verified 1944us version.
// ---------------------------------------------------------------------------
__global__ __launch_bounds__(NTHR) void gru_step(
    const unsigned short* __restrict__ wsw,
    const unsigned short* __restrict__ hhi_in,
    const unsigned short* __restrict__ hlo_in,
    unsigned short* __restrict__ hhi_out,
    unsigned short* __restrict__ hlo_out,
    const float* __restrict__ bias_ih, const float* __restrict__ bias_hh,
    const float* __restrict__ fc_w, float* __restrict__ ddot_t) {
  extern __shared__ char smem[];
  unsigned short* lds_w = (unsigned short*)smem;

  const int cb = blockIdx.x;
  const int rg = blockIdx.y;
  const int tid = threadIdx.x;
  const int lane = tid & 63;
  const int wave = tid >> 6;
  const int ln15 = lane & 15, quad = lane >> 4;
  const int j0 = cb * 16;

  const unsigned short* wsrc = wsw + (size_t)cb * 73728;
  for (int i = 0; i < 36; ++i) {
    const int c = wave * 36 + i;
    __builtin_amdgcn_global_load_lds(
        (const __attribute__((address_space(1))) unsigned int*)(wsrc + (size_t)c * 512 + lane * 8),
        (__attribute__((address_space(3))) unsigned int*)(lds_w + (size_t)c * 512),
        16, 0, 0);
  }

  const int j = j0 + ln15;
  const float bir = bias_ih[j], biz = bias_ih[Hn + j], bin = bias_ih[2 * Hn + j];
  const float bhr = bias_hh[j], bhz = bias_hh[Hn + j], bhn = bias_hh[2 * Hn + j];
  const float fw = fc_w[j];
  const int mrow0 = rg * 64 + wave * 16;

  unsigned short hoh[4], hol[4];
#pragma unroll
  for (int i = 0; i < 4; ++i) {
    size_t idx = (size_t)(mrow0 + quad * 4 + i) * Hn + j;
    hoh[i] = hhi_in[idx];
    hol[i] = hlo_in[idx];
  }

  const unsigned short* Ah_base = hhi_in + (size_t)(mrow0 + ln15) * Hn + quad * 8;
  const unsigned short* Al_base = hlo_in + (size_t)(mrow0 + ln15) * Hn + quad * 8;

  floatx4 acc[3];
#pragma unroll
  for (int g = 0; g < 3; ++g) acc[g] = (floatx4){0.f, 0.f, 0.f, 0.f};

  short8 Abh[2][4], Abl[2][4];
#pragma unroll
  for (int q = 0; q < 4; ++q) {
    Abh[0][q] = *(const short8*)(Ah_base + q * 32);
    Abl[0][q] = *(const short8*)(Al_base + q * 32);
  }

  __syncthreads();

#pragma unroll
  for (int c = 0; c < 6; ++c) {
    const int cur = c & 1, nxt = cur ^ 1;
    if (c < 5) {
#pragma unroll
      for (int q = 0; q < 4; ++q) {
        Abh[nxt][q] = *(const short8*)(Ah_base + ((c + 1) * 4 + q) * 32);
        Abl[nxt][q] = *(const short8*)(Al_base + ((c + 1) * 4 + q) * 32);
      }
    }
#pragma unroll
    for (int kk = 0; kk < 4; ++kk) {
      const int ks = c * 4 + kk;
#pragma unroll
      for (int g = 0; g < 3; ++g) {
        const int cbase = ((g * KS + ks) * 2) * 512 + lane * 8;
        short8 Bh = *(const short8*)(lds_w + cbase);
        short8 Bl = *(const short8*)(lds_w + cbase + 512);
        acc[g] = __builtin_amdgcn_mfma_f32_16x16x32_bf16(Abh[cur][kk], Bh, acc[g], 0, 0, 0);
        acc[g] = __builtin_amdgcn_mfma_f32_16x16x32_bf16(Abl[cur][kk], Bh, acc[g], 0, 0, 0);
        acc[g] = __builtin_amdgcn_mfma_f32_16x16x32_bf16(Abh[cur][kk], Bl, acc[g], 0, 0, 0);
      }
    }
  }

  float fcv[4];
#pragma unroll
  for (int i = 0; i < 4; ++i) {
    const int r = mrow0 + quad * 4 + i;
    float gr = bir + bhr + acc[0][i];
    float gz = biz + bhz + acc[1][i];
    float rr = 1.f / (1.f + __expf(-gr));
    float zz = 1.f / (1.f + __expf(-gz));
    float gn = bin + rr * (acc[2][i] + bhn);
    float nn = 1.f - 2.f / (1.f + __expf(2.f * gn));
    float hold = bf2f(hoh[i]) + bf2f(hol[i]);
    float hn = (1.f - zz) * nn + zz * hold;
    size_t idx = (size_t)r * Hn + j;
    unsigned short hb = f2bf(hn);
    hhi_out[idx] = hb;
    hlo_out[idx] = f2bf(hn - bf2f(hb));
    fcv[i] = hn * fw;
  }
#pragma unroll
  for (int i = 0; i < 4; ++i) {
    fcv[i] += __shfl_xor(fcv[i], 1);
    fcv[i] += __shfl_xor(fcv[i], 2);
    fcv[i] += __shfl_xor(fcv[i], 4);
    fcv[i] += __shfl_xor(fcv[i], 8);
  }
  if (ln15 == 0) {
#pragma unroll
    for (int i = 0; i < 4; ++i)
      atomicAdd(&ddot_t[mrow0 + quad * 4 + i], fcv[i]);
  }
}

// ---------------------------------------------------------------------------
// Post: softplus -> inclusive scan over T -> normalize -> assemble output.
// ---------------------------------------------------------------------------
__global__ void post_k(const float* __restrict__ ddot,
                       const float* __restrict__ fc_b,
                       const int* __restrict__ npred, float* __restrict__ out) {
  const int b = blockIdx.x;
  const int t = threadIdx.x;  // 0..127
  __shared__ float s[Tn];
  float x = ddot[(size_t)t * Bn + b] + fc_b[0];
  float sp = (x > 20.f) ? x : log1pf(__expf(x));
  s[t] = sp;
  __syncthreads();
  for (int off = 1; off < Tn; off <<= 1) {
    float v = s[t];
    float add = (t >= off) ? s[t - off] : 0.f;
    __syncthreads();
    s[t] = v + add;
    __syncthreads();
  }
  const int n = npred[b];
  const float last = s[n - 1] + 1e-6f;
  float body = (t < n) ? (s[t] / last) : 0.f;
  float* ob = out + (size_t)b * (Tn + 2);
  ob[1 + t] = body;
  if (t == 0) { ob[0] = 0.f; ob[Tn + 1] = 0.f; }
  __syncthreads();
  if (t == 0) ob[n + 1] = 1.f;
}

// ---------------------------------------------------------------------------
extern "C" void kernel_launch(void* const* d_in, const int* in_sizes, int n_in,
                              void* d_out, int out_size, void* d_ws, size_t ws_size,
                              hipStream_t stream) {
  const float* context   = (const float*)d_in[0];
  // d_in[1] = weight_ih: unused by the reference computation
  const float* weight_hh = (const float*)d_in[2];
  const float* bias_ih   = (const float*)d_in[3];
  const float* bias_hh   = (const float*)d_in[4];
  const float* fc_w      = (const float*)d_in[5];
  const float* fc_b      = (const float*)d_in[6];
  const int*   npred     = (const int*)d_in[7];
  float* out = (float*)d_out;

  char* ws = (char*)d_ws;
  size_t o = 0;
  unsigned short* hbase = (unsigned short*)(ws + o); o += (size_t)4 * Bn * Hn * 2;
  unsigned short* wsw   = (unsigned short*)(ws + o); o += (size_t)6 * Hn * Hn * 2;
  float* ddot = (float*)(ws + o); o += (size_t)Tn * Bn * 4;
  int* flags = (int*)(ws + o); o += (size_t)RGn * 128 * 4;
  // ~8.8 MB of d_ws

  swz_w<<<dim3((2304 * (Hn / 8) + 255) / 256), dim3(256), 0, stream>>>(weight_hh, wsw);
  init_h<<<dim3((Bn * Hn + 255) / 256), dim3(256), 0, stream>>>(context, hbase, ddot, flags);

  hipFuncSetAttribute((const void*)gru_all,
                      hipFuncAttributeMaxDynamicSharedMemorySize, SMEM_BYTES);

  const unsigned short* wsw_c = wsw;
  unsigned short* hb = hbase;
  const float* bih = bias_ih;
  const float* bhh = bias_hh;
  const float* fcw = fc_w;
  float* dd = ddot;
  int* fp = flags;
  void* args[] = {(void*)&wsw_c, (void*)&hb, (void*)&bih,
                  (void*)&bhh,  (void*)&fcw, (void*)&dd, (void*)&fp};
  hipError_t ce = hipLaunchCooperativeKernel((const void*)gru_all, dim3(NBLK),
                                             dim3(NTHR), args, SMEM_BYTES, stream);
  if (ce != hipSuccess) {
    // Fallback: proven per-step dispatch path (coherence via dispatch boundary)
    hipFuncSetAttribute((const void*)gru_step,
                        hipFuncAttributeMaxDynamicSharedMemorySize, SMEM_BYTES);
    const size_t N = (size_t)Bn * Hn;
    unsigned short* HHI[2] = {hbase, hbase + 2 * N};
    unsigned short* HLO[2] = {hbase + N, hbase + 3 * N};
    int cur = 0;
    for (int t = 0; t < Tn; ++t) {
      gru_step<<<dim3(CBn, RGn), dim3(NTHR), SMEM_BYTES, stream>>>(
          wsw, HHI[cur], HLO[cur], HHI[1 - cur], HLO[1 - cur],
          bias_ih, bias_hh, fc_w, ddot + (size_t)t * Bn);
      cur ^= 1;
    }
  }

  post_k<<<dim3(Bn), dim3(Tn), 0, stream>>>(ddot, fc_b, npred, out);
}

// Round 4
// 2315.129 us; speedup vs baseline: 1.6388x; 1.0600x over previous
//
#include <hip/hip_runtime.h>
#include <stdint.h>

// Problem constants (fixed by setup_inputs)
#define Bn 256
#define Hn 768
#define Tn 128
#define KS 24      // Hn/32 ksteps
#define CBn 48     // col-blocks (j-tiles of 16 hidden units x 3 gates)
#define RGn 4      // row-groups of 64 batch rows
#define NTHR 256   // 4 waves; wave w owns m-tile w (16 rows), all gates, full K
#define NBLK 192   // CBn * RGn
#define SMEM_BYTES 147456  // W slice hi+lo in LDS (dynamic)

typedef __attribute__((ext_vector_type(8))) short short8;   // 8 bf16
typedef __attribute__((ext_vector_type(4))) float floatx4;  // mfma C/D

static __device__ __forceinline__ unsigned short f2bf(float f) {
  unsigned int x = __float_as_uint(f);
  x += 0x7fffu + ((x >> 16) & 1u);
  return (unsigned short)(x >> 16);
}
static __device__ __forceinline__ float bf2f(unsigned short u) {
  return __uint_as_float(((unsigned int)u) << 16);
}

// ---------------------------------------------------------------------------
// Swizzle W_hh (2304x768 fp32 row-major) into slice-contiguous B-fragment
// order, bf16 hi/lo interleaved per chunk (unchanged).
// ---------------------------------------------------------------------------
__global__ void swz_w(const float* __restrict__ W,
                      unsigned short* __restrict__ wsw) {
  int i = blockIdx.x * blockDim.x + threadIdx.x;
  if (i >= 2304 * (Hn / 8)) return;
  int n  = i / (Hn / 8);
  int k0 = (i % (Hn / 8)) * 8;
  int g = n / Hn, jj = n % Hn;
  int cb = jj >> 4, l15 = jj & 15;
  int ks = k0 >> 5, k8 = (k0 >> 3) & 3;
  int lane = l15 + 16 * k8;
  unsigned short* slice = wsw + (size_t)cb * 73728;
  size_t offh = ((size_t)((g * KS + ks) * 2 + 0)) * 512 + (size_t)lane * 8;
  size_t offl = ((size_t)((g * KS + ks) * 2 + 1)) * 512 + (size_t)lane * 8;
  const float* src = W + (size_t)n * Hn + k0;
  short8 h8, l8;
#pragma unroll
  for (int q = 0; q < 8; ++q) {
    float w = src[q];
    unsigned short hb = f2bf(w);
    h8[q] = (short)hb;
    l8[q] = (short)f2bf(w - bf2f(hb));
  }
  *(short8*)(slice + offh) = h8;
  *(short8*)(slice + offl) = l8;
}

// ---------------------------------------------------------------------------
// Init: h0 planes (bf16 hi/lo) from context; zero ddot; zero barrier flags.
// hbase layout: [hhi0 | hlo0 | hhi1 | hlo1], each Bn*Hn elements.
// ---------------------------------------------------------------------------
__global__ void init_h(const float* __restrict__ ctx,
                       unsigned short* __restrict__ hbase,
                       float* __restrict__ ddot, int* __restrict__ flags) {
  int i = blockIdx.x * blockDim.x + threadIdx.x;
  if (i < Bn * Hn) {
    float c = ctx[i];
    unsigned short hb = f2bf(c);
    hbase[i] = hb;                            // hhi0
    hbase[Bn * Hn + i] = f2bf(c - bf2f(hb));  // hlo0
  }
  if (i < Tn * Bn) ddot[i] = 0.f;
  if (i < RGn * 128) flags[i] = 0;
}

// ---------------------------------------------------------------------------
// PERSISTENT cooperative kernel, two-level per-rg barrier (leader + done word).
//  - h stores: agent-scope relaxed atomics (sc1 write-through, no dirty L2).
//  - Arrive: vmcnt drain (h stores acked at coherence point), block sync,
//    tid0 stores epoch t+1 to its OWN flag slot (48 parallel stores, no RMW).
//  - Detect (r3 lesson): in r3 all 48 wave0s polled the 48 flags every ~64cyc
//    => ~170 line-requests/round/rg hammering 3-4 L3 slices; the LAST
//    arrival's flag store queued behind the read flood => multi-us detection.
//    Now only the LEADER (cb==0) polls the arrival flags; it then stores a
//    single done[rg] word; 47 followers poll that ONE word with all 64 lanes
//    on the SAME address (1 broadcast line-request/round/block, s_sleep(2)).
//    Shared-line request rate drops ~40x; arrival stores no longer contend.
//  - Hang-safety is mapping-independent (no XCD assumptions): monotone
//    epochs; leader stores done only after all flags >= t+1; a follower
//    passing the barrier implies the leader passed, implies every block's
//    reads of the old h buffer completed (same induction as before).
//  - Acquire: fence(acquire, agent) = flash invalidate; then ALL 6 A-chunks
//    prefetch up-front (1 wave/SIMD has no TLP to hide post-inv latency).
//  - ddot atomics deferred past the barrier (consumed only by post_k).
// ---------------------------------------------------------------------------
__global__ __launch_bounds__(NTHR, 1) void gru_all(
    const unsigned short* __restrict__ wsw,
    unsigned short* hbase,
    const float* __restrict__ bias_ih, const float* __restrict__ bias_hh,
    const float* __restrict__ fc_w, float* __restrict__ ddot,
    int* flags) {
  extern __shared__ char smem[];
  unsigned short* lds_w = (unsigned short*)smem;  // 144 chunks x 1 KiB

  const int bid = blockIdx.x;              // 0..191
  const int rg = (bid & 7) >> 1;           // XCD pair -> one row-group
  const int cb = ((bid >> 3) << 1) | (bid & 1);
  const int tid = threadIdx.x;
  const int lane = tid & 63;
  const int wave = tid >> 6;
  const int ln15 = lane & 15, quad = lane >> 4;
  const bool leader = (cb == 0);

  // ---- async W staging, ONCE ----
  const unsigned short* wsrc = wsw + (size_t)cb * 73728;
  for (int i = 0; i < 36; ++i) {
    const int c = wave * 36 + i;
    __builtin_amdgcn_global_load_lds(
        (const __attribute__((address_space(1))) unsigned int*)(wsrc + (size_t)c * 512 + lane * 8),
        (__attribute__((address_space(3))) unsigned int*)(lds_w + (size_t)c * 512),
        16, 0, 0);
  }

  // ---- per-lane constants ----
  const int j = cb * 16 + ln15;
  const float bir = bias_ih[j], biz = bias_ih[Hn + j], bin = bias_ih[2 * Hn + j];
  const float bhr = bias_hh[j], bhz = bias_hh[Hn + j], bhn = bias_hh[2 * Hn + j];
  const float fw = fc_w[j];
  const int mrow0 = rg * 64 + wave * 16;  // wave's 16 rows
  const size_t N = (size_t)Bn * Hn;
  const bool evenlane = ((ln15 & 1) == 0);
  int* const myflag = flags + rg * 128 + cb;
  int* const pollp  = flags + rg * 128 + ((lane < CBn) ? lane : (CBn - 1));
  int* const donep  = flags + rg * 128 + 64;  // own cache line (bytes 256..)

  __syncthreads();  // drains vmcnt(0): W staging complete; W read-only after

  float fcv[4];
  bool have_fc = false;
  int fc_t = 0, fc_r0 = 0;

  for (int t = 0; t < Tn; ++t) {
    const unsigned short* hhi_in = hbase + (size_t)(t & 1) * (2 * N);
    const unsigned short* hlo_in = hhi_in + N;
    unsigned short* hhi_out = hbase + (size_t)((t & 1) ^ 1) * (2 * N);
    unsigned short* hlo_out = hhi_out + N;

    const unsigned short* Ah_base = hhi_in + (size_t)(mrow0 + ln15) * Hn + quad * 8;
    const unsigned short* Al_base = hlo_in + (size_t)(mrow0 + ln15) * Hn + quad * 8;

    // ---- FULL A prefetch: all 6 chunks (48 b128 loads) issued up-front ----
    short8 Abh[6][4], Abl[6][4];
#pragma unroll
    for (int c = 0; c < 6; ++c) {
#pragma unroll
      for (int q = 0; q < 4; ++q) {
        Abh[c][q] = *(const short8*)(Ah_base + (c * 4 + q) * 32);
        Abl[c][q] = *(const short8*)(Al_base + (c * 4 + q) * 32);
      }
    }

    // h_old loads (epilogue inputs) -- issued after A (needed later)
    unsigned short hoh[4], hol[4];
#pragma unroll
    for (int i = 0; i < 4; ++i) {
      size_t idx = (size_t)(mrow0 + quad * 4 + i) * Hn + j;
      hoh[i] = hhi_in[idx];
      hol[i] = hlo_in[idx];
    }

    // deferred ddot atomics from previous step (overlap with A-load latency)
    if (have_fc) {
      if (ln15 == 0) {
#pragma unroll
        for (int i = 0; i < 4; ++i)
          atomicAdd(&ddot[(size_t)fc_t * Bn + fc_r0 + i], fcv[i]);
      }
      have_fc = false;
    }

    floatx4 acc[3];
#pragma unroll
    for (int g = 0; g < 3; ++g) acc[g] = (floatx4){0.f, 0.f, 0.f, 0.f};

#pragma unroll
    for (int c = 0; c < 6; ++c) {
#pragma unroll
      for (int kk = 0; kk < 4; ++kk) {
        const int ks = c * 4 + kk;
#pragma unroll
        for (int g = 0; g < 3; ++g) {
          const int cbase = ((g * KS + ks) * 2) * 512 + lane * 8;
          short8 Bh = *(const short8*)(lds_w + cbase);
          short8 Bl = *(const short8*)(lds_w + cbase + 512);
          acc[g] = __builtin_amdgcn_mfma_f32_16x16x32_bf16(Abh[c][kk], Bh, acc[g], 0, 0, 0);
          acc[g] = __builtin_amdgcn_mfma_f32_16x16x32_bf16(Abl[c][kk], Bh, acc[g], 0, 0, 0);
          acc[g] = __builtin_amdgcn_mfma_f32_16x16x32_bf16(Abh[c][kk], Bl, acc[g], 0, 0, 0);
        }
      }
    }

    // ---- epilogue: gates + h_new + fc partial (identical numerics) ----
    unsigned int ph[4], pl[4];
#pragma unroll
    for (int i = 0; i < 4; ++i) {
      float gr = bir + bhr + acc[0][i];
      float gz = biz + bhz + acc[1][i];
      float rr = 1.f / (1.f + __expf(-gr));
      float zz = 1.f / (1.f + __expf(-gz));
      float gn = bin + rr * (acc[2][i] + bhn);
      float nn = 1.f - 2.f / (1.f + __expf(2.f * gn));  // tanh
      float hold = bf2f(hoh[i]) + bf2f(hol[i]);
      float hn = (1.f - zz) * nn + zz * hold;
      unsigned short hb = f2bf(hn);
      ph[i] = (unsigned int)hb;
      pl[i] = (unsigned int)f2bf(hn - bf2f(hb));
      fcv[i] = hn * fw;
    }
    // pack adjacent-j pairs (lane^1 holds j^1; same rows) -> dword sc1 stores
#pragma unroll
    for (int i = 0; i < 4; ++i) {
      unsigned int oh = (unsigned int)__shfl_xor((int)ph[i], 1);
      unsigned int ol = (unsigned int)__shfl_xor((int)pl[i], 1);
      if (evenlane) {
        size_t idx = (size_t)(mrow0 + quad * 4 + i) * Hn + j;  // j even
        __hip_atomic_store((unsigned int*)(hhi_out + idx), ph[i] | (oh << 16),
                           __ATOMIC_RELAXED, __HIP_MEMORY_SCOPE_AGENT);
        __hip_atomic_store((unsigned int*)(hlo_out + idx), pl[i] | (ol << 16),
                           __ATOMIC_RELAXED, __HIP_MEMORY_SCOPE_AGENT);
      }
    }
    // fc partial reduce in-register (atomics deferred past the barrier)
#pragma unroll
    for (int i = 0; i < 4; ++i) {
      fcv[i] += __shfl_xor(fcv[i], 1);
      fcv[i] += __shfl_xor(fcv[i], 2);
      fcv[i] += __shfl_xor(fcv[i], 4);
      fcv[i] += __shfl_xor(fcv[i], 8);
    }
    have_fc = true;
    fc_t = t;
    fc_r0 = mrow0 + quad * 4;

    // ---- two-level per-rg barrier (skip after last step) ----
    if (t < Tn - 1) {
      asm volatile("s_waitcnt vmcnt(0)" ::: "memory");  // h stores acked
      __syncthreads();                                  // whole block drained
      if (tid == 0)
        __hip_atomic_store(myflag, t + 1, __ATOMIC_RELAXED,
                           __HIP_MEMORY_SCOPE_AGENT);   // own slot: no RMW
      if (wave == 0) {
        if (leader) {
          // leader: poll the 48 arrival flags (3-4 line reqs/round, 1 wave)
          for (;;) {
            int v = __hip_atomic_load(pollp, __ATOMIC_RELAXED,
                                      __HIP_MEMORY_SCOPE_AGENT);
            if (__all(v >= t + 1)) break;
            __builtin_amdgcn_s_sleep(1);
          }
          if (lane == 0)
            __hip_atomic_store(donep, t + 1, __ATOMIC_RELAXED,
                               __HIP_MEMORY_SCOPE_AGENT);
        } else {
          // followers: poll ONE broadcast word (same addr across 64 lanes
          // => a single line request per round), low rate
          for (;;) {
            int v = __hip_atomic_load(donep, __ATOMIC_RELAXED,
                                      __HIP_MEMORY_SCOPE_AGENT);
            if (v >= t + 1) break;
            __builtin_amdgcn_s_sleep(2);
          }
        }
      }
      __syncthreads();
      // flash-invalidate stale L1/L2 h lines; loads then refill from L3
      __builtin_amdgcn_fence(__ATOMIC_ACQUIRE, "agent");
    }
  }

  // last step's ddot contribution
  if (ln15 == 0) {
#pragma unroll
    for (int i = 0; i < 4; ++i)
      atomicAdd(&ddot[(size_t)fc_t * Bn + fc_r0 + i], fcv[i]);
  }
}

// ---------------------------------------------------------------------------
// Fallback: proven one-step-per-dispatch kernel (used only if cooperative
// launch is rejected). Unchanged from the verified 1944us version.
// ---------------------------------------------------------------------------
__global__ __launch_bounds__(NTHR) void gru_step(
    const unsigned short* __restrict__ wsw,
    const unsigned short* __restrict__ hhi_in,
    const unsigned short* __restrict__ hlo_in,
    unsigned short* __restrict__ hhi_out,
    unsigned short* __restrict__ hlo_out,
    const float* __restrict__ bias_ih, const float* __restrict__ bias_hh,
    const float* __restrict__ fc_w, float* __restrict__ ddot_t) {
  extern __shared__ char smem[];
  unsigned short* lds_w = (unsigned short*)smem;

  const int cb = blockIdx.x;
  const int rg = blockIdx.y;
  const int tid = threadIdx.x;
  const int lane = tid & 63;
  const int wave = tid >> 6;
  const int ln15 = lane & 15, quad = lane >> 4;
  const int j0 = cb * 16;

  const unsigned short* wsrc = wsw + (size_t)cb * 73728;
  for (int i = 0; i < 36; ++i) {
    const int c = wave * 36 + i;
    __builtin_amdgcn_global_load_lds(
        (const __attribute__((address_space(1))) unsigned int*)(wsrc + (size_t)c * 512 + lane * 8),
        (__attribute__((address_space(3))) unsigned int*)(lds_w + (size_t)c * 512),
        16, 0, 0);
  }

  const int j = j0 + ln15;
  const float bir = bias_ih[j], biz = bias_ih[Hn + j], bin = bias_ih[2 * Hn + j];
  const float bhr = bias_hh[j], bhz = bias_hh[Hn + j], bhn = bias_hh[2 * Hn + j];
  const float fw = fc_w[j];
  const int mrow0 = rg * 64 + wave * 16;

  unsigned short hoh[4], hol[4];
#pragma unroll
  for (int i = 0; i < 4; ++i) {
    size_t idx = (size_t)(mrow0 + quad * 4 + i) * Hn + j;
    hoh[i] = hhi_in[idx];
    hol[i] = hlo_in[idx];
  }

  const unsigned short* Ah_base = hhi_in + (size_t)(mrow0 + ln15) * Hn + quad * 8;
  const unsigned short* Al_base = hlo_in + (size_t)(mrow0 + ln15) * Hn + quad * 8;

  floatx4 acc[3];
#pragma unroll
  for (int g = 0; g < 3; ++g) acc[g] = (floatx4){0.f, 0.f, 0.f, 0.f};

  short8 Abh[2][4], Abl[2][4];
#pragma unroll
  for (int q = 0; q < 4; ++q) {
    Abh[0][q] = *(const short8*)(Ah_base + q * 32);
    Abl[0][q] = *(const short8*)(Al_base + q * 32);
  }

  __syncthreads();

#pragma unroll
  for (int c = 0; c < 6; ++c) {
    const int cur = c & 1, nxt = cur ^ 1;
    if (c < 5) {
#pragma unroll
      for (int q = 0; q < 4; ++q) {
        Abh[nxt][q] = *(const short8*)(Ah_base + ((c + 1) * 4 + q) * 32);
        Abl[nxt][q] = *(const short8*)(Al_base + ((c + 1) * 4 + q) * 32);
      }
    }
#pragma unroll
    for (int kk = 0; kk < 4; ++kk) {
      const int ks = c * 4 + kk;
#pragma unroll
      for (int g = 0; g < 3; ++g) {
        const int cbase = ((g * KS + ks) * 2) * 512 + lane * 8;
        short8 Bh = *(const short8*)(lds_w + cbase);
        short8 Bl = *(const short8*)(lds_w + cbase + 512);
        acc[g] = __builtin_amdgcn_mfma_f32_16x16x32_bf16(Abh[cur][kk], Bh, acc[g], 0, 0, 0);
        acc[g] = __builtin_amdgcn_mfma_f32_16x16x32_bf16(Abl[cur][kk], Bh, acc[g], 0, 0, 0);
        acc[g] = __builtin_amdgcn_mfma_f32_16x16x32_bf16(Abh[cur][kk], Bl, acc[g], 0, 0, 0);
      }
    }
  }

  float fcv[4];
#pragma unroll
  for (int i = 0; i < 4; ++i) {
    const int r = mrow0 + quad * 4 + i;
    float gr = bir + bhr + acc[0][i];
    float gz = biz + bhz + acc[1][i];
    float rr = 1.f / (1.f + __expf(-gr));
    float zz = 1.f / (1.f + __expf(-gz));
    float gn = bin + rr * (acc[2][i] + bhn);
    float nn = 1.f - 2.f / (1.f + __expf(2.f * gn));
    float hold = bf2f(hoh[i]) + bf2f(hol[i]);
    float hn = (1.f - zz) * nn + zz * hold;
    size_t idx = (size_t)r * Hn + j;
    unsigned short hb = f2bf(hn);
    hhi_out[idx] = hb;
    hlo_out[idx] = f2bf(hn - bf2f(hb));
    fcv[i] = hn * fw;
  }
#pragma unroll
  for (int i = 0; i < 4; ++i) {
    fcv[i] += __shfl_xor(fcv[i], 1);
    fcv[i] += __shfl_xor(fcv[i], 2);
    fcv[i] += __shfl_xor(fcv[i], 4);
    fcv[i] += __shfl_xor(fcv[i], 8);
  }
  if (ln15 == 0) {
#pragma unroll
    for (int i = 0; i < 4; ++i)
      atomicAdd(&ddot_t[mrow0 + quad * 4 + i], fcv[i]);
  }
}

// ---------------------------------------------------------------------------
// Post: softplus -> inclusive scan over T -> normalize -> assemble output.
// ---------------------------------------------------------------------------
__global__ void post_k(const float* __restrict__ ddot,
                       const float* __restrict__ fc_b,
                       const int* __restrict__ npred, float* __restrict__ out) {
  const int b = blockIdx.x;
  const int t = threadIdx.x;  // 0..127
  __shared__ float s[Tn];
  float x = ddot[(size_t)t * Bn + b] + fc_b[0];
  float sp = (x > 20.f) ? x : log1pf(__expf(x));
  s[t] = sp;
  __syncthreads();
  for (int off = 1; off < Tn; off <<= 1) {
    float v = s[t];
    float add = (t >= off) ? s[t - off] : 0.f;
    __syncthreads();
    s[t] = v + add;
    __syncthreads();
  }
  const int n = npred[b];
  const float last = s[n - 1] + 1e-6f;
  float body = (t < n) ? (s[t] / last) : 0.f;
  float* ob = out + (size_t)b * (Tn + 2);
  ob[1 + t] = body;
  if (t == 0) { ob[0] = 0.f; ob[Tn + 1] = 0.f; }
  __syncthreads();
  if (t == 0) ob[n + 1] = 1.f;
}

// ---------------------------------------------------------------------------
extern "C" void kernel_launch(void* const* d_in, const int* in_sizes, int n_in,
                              void* d_out, int out_size, void* d_ws, size_t ws_size,
                              hipStream_t stream) {
  const float* context   = (const float*)d_in[0];
  // d_in[1] = weight_ih: unused by the reference computation
  const float* weight_hh = (const float*)d_in[2];
  const float* bias_ih   = (const float*)d_in[3];
  const float* bias_hh   = (const float*)d_in[4];
  const float* fc_w      = (const float*)d_in[5];
  const float* fc_b      = (const float*)d_in[6];
  const int*   npred     = (const int*)d_in[7];
  float* out = (float*)d_out;

  char* ws = (char*)d_ws;
  size_t o = 0;
  unsigned short* hbase = (unsigned short*)(ws + o); o += (size_t)4 * Bn * Hn * 2;
  unsigned short* wsw   = (unsigned short*)(ws + o); o += (size_t)6 * Hn * Hn * 2;
  float* ddot = (float*)(ws + o); o += (size_t)Tn * Bn * 4;
  int* flags = (int*)(ws + o); o += (size_t)RGn * 128 * 4;
  // ~8.8 MB of d_ws

  swz_w<<<dim3((2304 * (Hn / 8) + 255) / 256), dim3(256), 0, stream>>>(weight_hh, wsw);
  init_h<<<dim3((Bn * Hn + 255) / 256), dim3(256), 0, stream>>>(context, hbase, ddot, flags);

  hipFuncSetAttribute((const void*)gru_all,
                      hipFuncAttributeMaxDynamicSharedMemorySize, SMEM_BYTES);

  const unsigned short* wsw_c = wsw;
  unsigned short* hb = hbase;
  const float* bih = bias_ih;
  const float* bhh = bias_hh;
  const float* fcw = fc_w;
  float* dd = ddot;
  int* fp = flags;
  void* args[] = {(void*)&wsw_c, (void*)&hb, (void*)&bih,
                  (void*)&bhh,  (void*)&fcw, (void*)&dd, (void*)&fp};
  hipError_t ce = hipLaunchCooperativeKernel((const void*)gru_all, dim3(NBLK),
                                             dim3(NTHR), args, SMEM_BYTES, stream);
  if (ce != hipSuccess) {
    // Fallback: proven per-step dispatch path (coherence via dispatch boundary)
    hipFuncSetAttribute((const void*)gru_step,
                        hipFuncAttributeMaxDynamicSharedMemorySize, SMEM_BYTES);
    const size_t N = (size_t)Bn * Hn;
    unsigned short* HHI[2] = {hbase, hbase + 2 * N};
    unsigned short* HLO[2] = {hbase + N, hbase + 3 * N};
    int cur = 0;
    for (int t = 0; t < Tn; ++t) {
      gru_step<<<dim3(CBn, RGn), dim3(NTHR), SMEM_BYTES, stream>>>(
          wsw, HHI[cur], HLO[cur], HHI[1 - cur], HLO[1 - cur],
          bias_ih, bias_hh, fc_w, ddot + (size_t)t * Bn);
      cur ^= 1;
    }
  }

  post_k<<<dim3(Bn), dim3(Tn), 0, stream>>>(ddot, fc_b, npred, out);
}